// Round 6
// baseline (145.205 us; speedup 1.0000x reference)
//
#include <hip/hip_runtime.h>
#include <math.h>

#define NN 512
#define CC 256
#define HH 8
#define DH 32

typedef float vf4 __attribute__((ext_vector_type(4)));

// ---------------- Kernel A: projections + Wp-fold ----------------
// grid = 256 (two rows n per block), block = 512
__global__ __launch_bounds__(512) void proj_kernel(
    const float* __restrict__ xq, const float* __restrict__ xk, const float* __restrict__ xv,
    const float* __restrict__ Wq, const float* __restrict__ bq,
    const float* __restrict__ Wk, const float* __restrict__ bk,
    const float* __restrict__ Wv, const float* __restrict__ bv,
    const float* __restrict__ Wp, const float* __restrict__ bp,
    float* __restrict__ qf, float* __restrict__ kf, float* __restrict__ vf,
    float* __restrict__ qw, float* __restrict__ qbp)
{
    __shared__ float x_lds[2][3][CC];
    __shared__ float q_lds[2][CC];
    const int t = threadIdx.x;
    const int n0 = blockIdx.x * 2;

    if (t < 384) {
        int hh = t / 192, rem = t % 192;
        int X = rem >> 6, c4 = (rem & 63) * 4;
        const float* xs = (X == 0) ? xq : (X == 1) ? xk : xv;
        *reinterpret_cast<float4*>(&x_lds[hh][X][c4]) =
            *reinterpret_cast<const float4*>(xs + (size_t)(n0 + hh) * CC + c4);
    }
    __syncthreads();

    const int half = t >> 8, j = t & 255;
    const int n = n0 + half;
    {
        float accq = 0.f, acck = 0.f, accv = 0.f;
        const float* wq = Wq + (size_t)j * CC;
        const float* wk = Wk + (size_t)j * CC;
        const float* wv = Wv + (size_t)j * CC;
        #pragma unroll 4
        for (int k4 = 0; k4 < CC / 4; ++k4) {
            float4 a = *reinterpret_cast<const float4*>(wq + k4 * 4);
            float4 b = *reinterpret_cast<const float4*>(wk + k4 * 4);
            float4 d = *reinterpret_cast<const float4*>(wv + k4 * 4);
            const float* x0 = &x_lds[half][0][k4 * 4];
            const float* x1 = &x_lds[half][1][k4 * 4];
            const float* x2 = &x_lds[half][2][k4 * 4];
            accq += x0[0]*a.x + x0[1]*a.y + x0[2]*a.z + x0[3]*a.w;
            acck += x1[0]*b.x + x1[1]*b.y + x1[2]*b.z + x1[3]*b.w;
            accv += x2[0]*d.x + x2[1]*d.y + x2[2]*d.z + x2[3]*d.w;
        }
        float vq = accq + bq[j];
        kf[(size_t)n * CC + j] = acck + bk[j];
        vf[(size_t)n * CC + j] = accv + bv[j];
        qf[(size_t)n * CC + j] = vq;
        q_lds[half][j] = vq;
    }
    __syncthreads();

    // qw[n][h][j] = sum_c q[h*32+c] * Wp[h*32+c][j]
    #pragma unroll
    for (int h = 0; h < HH; ++h) {
        float acc = 0.f;
        #pragma unroll 8
        for (int cc = 0; cc < DH; ++cc)
            acc += q_lds[half][h * DH + cc] * Wp[(size_t)(h * DH + cc) * CC + j];
        qw[((size_t)n * HH + h) * CC + j] = acc;
    }
    if (t < 16) {
        int hf = t >> 3, h = t & 7;
        float s = 0.f;
        for (int cc = 0; cc < DH; ++cc) s += q_lds[hf][h * DH + cc] * bp[h * DH + cc];
        qbp[(size_t)(n0 + hf) * HH + h] = s;
    }
}

// 16-lane tree reduce of 8 head-partials; lane c (0..15) ends with head
// h = (c&1)*4 + (c&2) + ((c>>2)&1) in u0 (valid for c<8; c>=8 duplicates).
__device__ __forceinline__ float reduce8(const float a[HH], int c) {
    const bool b1 = (c & 1), b2 = (c & 2), b4 = (c & 4);
    float t0 = b1 ? a[0] : a[4], t1 = b1 ? a[1] : a[5],
          t2 = b1 ? a[2] : a[6], t3 = b1 ? a[3] : a[7];
    float r0 = (b1 ? a[4] : a[0]) + __shfl_xor(t0, 1);
    float r1 = (b1 ? a[5] : a[1]) + __shfl_xor(t1, 1);
    float r2 = (b1 ? a[6] : a[2]) + __shfl_xor(t2, 1);
    float r3 = (b1 ? a[7] : a[3]) + __shfl_xor(t3, 1);
    t0 = b2 ? r0 : r2; t1 = b2 ? r1 : r3;
    float s0 = (b2 ? r2 : r0) + __shfl_xor(t0, 2);
    float s1 = (b2 ? r3 : r1) + __shfl_xor(t1, 2);
    t0 = b4 ? s0 : s1;
    float u0 = (b4 ? s1 : s0) + __shfl_xor(t0, 4);
    u0 += __shfl_xor(u0, 8);
    return u0;
}

// ---------------- Kernel B: e-scores + E-stream + softmax + hidden ----------------
// one block per n, 512 threads (8 waves); wave w owns rows m in [64w, 64w+64)
__global__ __launch_bounds__(512, 2) void attn_kernel(
    const float* __restrict__ E, const float* __restrict__ qf,
    const float* __restrict__ kf, const float* __restrict__ vf,
    const float* __restrict__ qw, const float* __restrict__ qbp,
    float* __restrict__ attn_out, float* __restrict__ out_hidden)
{
    const int n = blockIdx.x;
    const int t = threadIdx.x;
    const int w = t >> 6, l = t & 63;
    const int r = l >> 4, c = l & 15;

    __shared__ float qw_lds[HH][CC];      // 8 KB; reused as hidden partials later
    __shared__ float s_lds[HH][NN + 4];   // 16.1 KB

    // stage qw: 512 threads x 1 float4 = 8 KB, coalesced
    {
        float4 v = *reinterpret_cast<const float4*>(qw + (size_t)n * HH * CC + t * 4);
        reinterpret_cast<float4*>(qw_lds)[t] = v;
    }
    __syncthreads();

    const int mbase = w * 64;

    // ---- k-pass: seed s_lds with scores_e = q[n] . k[m]  (k is L2-resident) ----
    {
        float4 q4[4];
        #pragma unroll
        for (int co = 0; co < 4; ++co)
            q4[co] = *reinterpret_cast<const float4*>(qf + (size_t)n * CC + co * 64 + c * 4);

        for (int g = 0; g < 4; ++g) {
            float acc[4][HH];
            #pragma unroll
            for (int it = 0; it < 4; ++it)
                #pragma unroll
                for (int h = 0; h < HH; ++h) acc[it][h] = 0.f;

            #pragma unroll
            for (int co = 0; co < 4; ++co) {
                const int o = co * 64 + c * 4;
                #pragma unroll
                for (int it = 0; it < 4; ++it) {
                    const int m = mbase + g * 16 + it * 4 + r;
                    float4 k4 = *reinterpret_cast<const float4*>(kf + (size_t)m * CC + o);
                    float kd = k4.x * q4[co].x + k4.y * q4[co].y +
                               k4.z * q4[co].z + k4.w * q4[co].w;
                    acc[it][2 * co    ] += (c & 8) ? 0.f : kd;
                    acc[it][2 * co + 1] += (c & 8) ? kd : 0.f;
                }
            }
            #pragma unroll
            for (int it = 0; it < 4; ++it) {
                float u0 = reduce8(acc[it], c);
                if (!(c & 8)) {
                    int h = (c & 1) * 4 + (c & 2) + ((c >> 2) & 1);
                    s_lds[h][mbase + g * 16 + it * 4 + r] = u0;  // seed (banks 4h+r)
                }
            }
        }
    }

    // ---- E-pass: stream E[n] (nontemporal; single-use), 2-deep pipeline ----
    const float* Ebase = E + (size_t)n * NN * CC;
    {
        vf4 ebuf[2][4];
        #pragma unroll
        for (int it = 0; it < 4; ++it)
            ebuf[0][it] = __builtin_nontemporal_load(reinterpret_cast<const vf4*>(
                Ebase + (size_t)(mbase + it * 4 + r) * CC + c * 4));

        for (int g = 0; g < 4; ++g) {
            float acc[4][HH];
            #pragma unroll
            for (int it = 0; it < 4; ++it)
                #pragma unroll
                for (int h = 0; h < HH; ++h) acc[it][h] = 0.f;

            #pragma unroll
            for (int co = 0; co < 4; ++co) {
                const int cur = co & 1;          // parity of gc=g*4+co (g*4 even)
                // prefetch next phase into the other buffer
                if (g < 3 || co < 3) {
                    const int cn = (co + 1) & 3;
                    const int gn = (co == 3) ? g + 1 : g;
                    #pragma unroll
                    for (int it = 0; it < 4; ++it)
                        ebuf[cur ^ 1][it] = __builtin_nontemporal_load(
                            reinterpret_cast<const vf4*>(
                                Ebase + (size_t)(mbase + gn * 16 + it * 4 + r) * CC +
                                cn * 64 + c * 4));
                }
                const int o = co * 64 + c * 4;
                #pragma unroll
                for (int h = 0; h < HH; ++h) {
                    float4 wv = *reinterpret_cast<const float4*>(&qw_lds[h][o]);
                    #pragma unroll
                    for (int it = 0; it < 4; ++it)
                        acc[it][h] += ebuf[cur][it][0] * wv.x + ebuf[cur][it][1] * wv.y +
                                      ebuf[cur][it][2] * wv.z + ebuf[cur][it][3] * wv.w;
                }
            }
            #pragma unroll
            for (int it = 0; it < 4; ++it) {
                float u0 = reduce8(acc[it], c);
                if (!(c & 8)) {
                    int h = (c & 1) * 4 + (c & 2) + ((c >> 2) & 1);
                    s_lds[h][mbase + g * 16 + it * 4 + r] += u0;
                }
            }
        }
    }
    __syncthreads();

    // softmax: wave w handles head w over all 512 m (bias + scale folded)
    {
        const int h = w;
        const float qb = qbp[(size_t)n * HH + h];
        const float scale = 0.17677669529663687f;  // 1/sqrt(32)
        float vals[8];
        float mx = -1e30f;
        #pragma unroll
        for (int i = 0; i < 8; ++i) {
            vals[i] = (s_lds[h][l + i * 64] + qb) * scale;
            mx = fmaxf(mx, vals[i]);
        }
        #pragma unroll
        for (int off = 32; off > 0; off >>= 1) mx = fmaxf(mx, __shfl_xor(mx, off));
        float sum = 0.f;
        #pragma unroll
        for (int i = 0; i < 8; ++i) { vals[i] = __expf(vals[i] - mx); sum += vals[i]; }
        #pragma unroll
        for (int off = 32; off > 0; off >>= 1) sum += __shfl_xor(sum, off);
        float inv = 1.0f / sum;
        #pragma unroll
        for (int i = 0; i < 8; ++i) {
            float p = vals[i] * inv;
            int m = l + i * 64;
            s_lds[h][m] = p;
            __builtin_nontemporal_store(p, attn_out + ((size_t)h * NN + n) * NN + m);
        }
    }
    __syncthreads();

    // hidden[n][j] = sum_m attn[h][m] * v[m][j], h = j>>5 (v is L2-resident)
    {
        float* part = &qw_lds[0][0];       // reuse qw_lds (8 KB) as partial buffer
        const int quad = t & 63;           // output cols quad*4..quad*4+3
        const int slice = w;               // m slice of 64
        const int h = quad >> 3;
        float4 a4 = {0.f, 0.f, 0.f, 0.f};
        const float* vb = vf + quad * 4;
        for (int mm = 0; mm < 64; ++mm) {
            int m = slice * 64 + mm;
            float a = s_lds[h][m];
            float4 vv = *reinterpret_cast<const float4*>(vb + (size_t)m * CC);
            a4.x += a * vv.x; a4.y += a * vv.y; a4.z += a * vv.z; a4.w += a * vv.w;
        }
        __syncthreads();                    // qw_lds reads are long done; re-purpose
        *reinterpret_cast<float4*>(&part[slice * 256 + quad * 4]) = a4;
    }
    __syncthreads();
    if (t < 256) {
        const float* part = &qw_lds[0][0];
        float s = 0.f;
        #pragma unroll
        for (int sl = 0; sl < 8; ++sl) s += part[sl * 256 + t];
        out_hidden[(size_t)n * CC + t] = s;
    }
}

// ---------------- launch ----------------
extern "C" void kernel_launch(void* const* d_in, const int* in_sizes, int n_in,
                              void* d_out, int out_size, void* d_ws, size_t ws_size,
                              hipStream_t stream) {
    const float* xq = (const float*)d_in[0];
    const float* xk = (const float*)d_in[1];
    const float* xv = (const float*)d_in[2];
    const float* E  = (const float*)d_in[3];
    const float* Wq = (const float*)d_in[4];
    const float* bq = (const float*)d_in[5];
    const float* Wk = (const float*)d_in[6];
    const float* bk = (const float*)d_in[7];
    const float* Wv = (const float*)d_in[8];
    const float* bv = (const float*)d_in[9];
    const float* Wp = (const float*)d_in[10];
    const float* bp = (const float*)d_in[11];

    float* ws = (float*)d_ws;
    float* qf  = ws;                        // 512*256
    float* kf  = qf + NN * CC;              // 512*256
    float* vf  = kf + NN * CC;              // 512*256
    float* qw  = vf + NN * CC;              // 512*8*256
    float* qbp = qw + (size_t)NN * HH * CC; // 512*8

    float* out_hidden = (float*)d_out;            // 512*256
    float* out_attn   = out_hidden + NN * CC;     // 8*512*512

    proj_kernel<<<NN / 2, 512, 0, stream>>>(xq, xk, xv, Wq, bq, Wk, bk, Wv, bv, Wp, bp,
                                            qf, kf, vf, qw, qbp);
    attn_kernel<<<NN, 512, 0, stream>>>(E, qf, kf, vf, qw, qbp, out_attn, out_hidden);
}

// Round 8
// 138.539 us; speedup vs baseline: 1.0481x; 1.0481x over previous
//
#include <hip/hip_runtime.h>
#include <math.h>

#define NN 512
#define CC 256
#define HH 8
#define DH 32

typedef float vf4 __attribute__((ext_vector_type(4)));

// ---------------- Kernel A: projections + Wp-fold ----------------
// grid = 256 (two rows n per block), block = 512
__global__ __launch_bounds__(512) void proj_kernel(
    const float* __restrict__ xq, const float* __restrict__ xk, const float* __restrict__ xv,
    const float* __restrict__ Wq, const float* __restrict__ bq,
    const float* __restrict__ Wk, const float* __restrict__ bk,
    const float* __restrict__ Wv, const float* __restrict__ bv,
    const float* __restrict__ Wp, const float* __restrict__ bp,
    float* __restrict__ qf, float* __restrict__ kf, float* __restrict__ vf,
    float* __restrict__ qw, float* __restrict__ qbp)
{
    __shared__ float x_lds[2][3][CC];
    __shared__ float q_lds[2][CC];
    const int t = threadIdx.x;
    const int n0 = blockIdx.x * 2;

    if (t < 384) {
        int hh = t / 192, rem = t % 192;
        int X = rem >> 6, c4 = (rem & 63) * 4;
        const float* xs = (X == 0) ? xq : (X == 1) ? xk : xv;
        *reinterpret_cast<float4*>(&x_lds[hh][X][c4]) =
            *reinterpret_cast<const float4*>(xs + (size_t)(n0 + hh) * CC + c4);
    }
    __syncthreads();

    const int half = t >> 8, j = t & 255;
    const int n = n0 + half;
    {
        float accq = 0.f, acck = 0.f, accv = 0.f;
        const float* wq = Wq + (size_t)j * CC;
        const float* wk = Wk + (size_t)j * CC;
        const float* wv = Wv + (size_t)j * CC;
        #pragma unroll 4
        for (int k4 = 0; k4 < CC / 4; ++k4) {
            float4 a = *reinterpret_cast<const float4*>(wq + k4 * 4);
            float4 b = *reinterpret_cast<const float4*>(wk + k4 * 4);
            float4 d = *reinterpret_cast<const float4*>(wv + k4 * 4);
            const float* x0 = &x_lds[half][0][k4 * 4];
            const float* x1 = &x_lds[half][1][k4 * 4];
            const float* x2 = &x_lds[half][2][k4 * 4];
            accq += x0[0]*a.x + x0[1]*a.y + x0[2]*a.z + x0[3]*a.w;
            acck += x1[0]*b.x + x1[1]*b.y + x1[2]*b.z + x1[3]*b.w;
            accv += x2[0]*d.x + x2[1]*d.y + x2[2]*d.z + x2[3]*d.w;
        }
        float vq = accq + bq[j];
        kf[(size_t)n * CC + j] = acck + bk[j];
        vf[(size_t)n * CC + j] = accv + bv[j];
        qf[(size_t)n * CC + j] = vq;
        q_lds[half][j] = vq;
    }
    __syncthreads();

    // qw fold: within each half, thread -> (head-pair hp, j-quad jq); float4 Wp loads
    {
        const int jq = t & 63;
        const int hp = (t >> 6) & 3;
        const int h0 = 2 * hp, h1 = h0 + 1;
        float4 a0 = {0.f, 0.f, 0.f, 0.f}, a1 = {0.f, 0.f, 0.f, 0.f};
        #pragma unroll
        for (int cc = 0; cc < DH; ++cc) {
            float q0 = q_lds[half][h0 * DH + cc];
            float q1 = q_lds[half][h1 * DH + cc];
            float4 w0 = *reinterpret_cast<const float4*>(Wp + (size_t)(h0 * DH + cc) * CC + jq * 4);
            float4 w1 = *reinterpret_cast<const float4*>(Wp + (size_t)(h1 * DH + cc) * CC + jq * 4);
            a0.x += q0 * w0.x; a0.y += q0 * w0.y; a0.z += q0 * w0.z; a0.w += q0 * w0.w;
            a1.x += q1 * w1.x; a1.y += q1 * w1.y; a1.z += q1 * w1.z; a1.w += q1 * w1.w;
        }
        *reinterpret_cast<float4*>(qw + ((size_t)n * HH + h0) * CC + jq * 4) = a0;
        *reinterpret_cast<float4*>(qw + ((size_t)n * HH + h1) * CC + jq * 4) = a1;
    }
    if (t < 16) {
        int hf = t >> 3, h = t & 7;
        float s = 0.f;
        for (int cc = 0; cc < DH; ++cc) s += q_lds[hf][h * DH + cc] * bp[h * DH + cc];
        qbp[(size_t)(n0 + hf) * HH + h] = s;
    }
}

// 16-lane tree reduce of 8 head-partials; lane c (0..15) ends with head
// h = (c&1)*4 + (c&2) + ((c>>2)&1) in u0 (valid for c<8; c>=8 duplicates).
__device__ __forceinline__ float reduce8(const float a[HH], int c) {
    const bool b1 = (c & 1), b2 = (c & 2), b4 = (c & 4);
    float t0 = b1 ? a[0] : a[4], t1 = b1 ? a[1] : a[5],
          t2 = b1 ? a[2] : a[6], t3 = b1 ? a[3] : a[7];
    float r0 = (b1 ? a[4] : a[0]) + __shfl_xor(t0, 1);
    float r1 = (b1 ? a[5] : a[1]) + __shfl_xor(t1, 1);
    float r2 = (b1 ? a[6] : a[2]) + __shfl_xor(t2, 1);
    float r3 = (b1 ? a[7] : a[3]) + __shfl_xor(t3, 1);
    t0 = b2 ? r0 : r2; t1 = b2 ? r1 : r3;
    float s0 = (b2 ? r2 : r0) + __shfl_xor(t0, 2);
    float s1 = (b2 ? r3 : r1) + __shfl_xor(t1, 2);
    t0 = b4 ? s0 : s1;
    float u0 = (b4 ? s1 : s0) + __shfl_xor(t0, 4);
    u0 += __shfl_xor(u0, 8);
    return u0;
}

// ---------------- Kernel B: e-scores + E-stream + softmax + hidden ----------------
// one block per n, 512 threads (8 waves); wave w owns rows m in [64w, 64w+64)
__global__ __launch_bounds__(512, 2) void attn_kernel(
    const float* __restrict__ E, const float* __restrict__ qf,
    const float* __restrict__ kf, const float* __restrict__ vf,
    const float* __restrict__ qw, const float* __restrict__ qbp,
    float* __restrict__ attn_out, float* __restrict__ out_hidden)
{
    const int n = blockIdx.x;
    const int t = threadIdx.x;
    const int w = t >> 6, l = t & 63;
    const int r = l >> 4, c = l & 15;
    // channel de-aliasing rotations: across the 8 waves of a block the
    // instantaneous (g,co) phase offsets cover all 4 column quarters and
    // both 16KB halves -> reads spread over all HBM channels.
    const int Rg = (w + n) & 3;
    const int Rc = (3 * w + n) & 3;

    __shared__ float qw_lds[HH][CC];      // 8 KB; reused as hidden partials later
    __shared__ float s_lds[HH][NN + 4];   // 16.1 KB

    // stage qw: 512 threads x 1 float4 = 8 KB, coalesced
    {
        float4 v = *reinterpret_cast<const float4*>(qw + (size_t)n * HH * CC + t * 4);
        reinterpret_cast<float4*>(qw_lds)[t] = v;
    }
    __syncthreads();

    const int mb = w * 64;

    // ---- k-pass: seed s_lds with scores_e = q[n] . k[m]  (k is L2-resident) ----
    {
        float4 q4[4];
        #pragma unroll
        for (int co = 0; co < 4; ++co)
            q4[co] = *reinterpret_cast<const float4*>(qf + (size_t)n * CC + co * 64 + c * 4);

        for (int g = 0; g < 4; ++g) {
            float acc[4][HH];
            #pragma unroll
            for (int it = 0; it < 4; ++it)
                #pragma unroll
                for (int h = 0; h < HH; ++h) acc[it][h] = 0.f;

            #pragma unroll
            for (int co = 0; co < 4; ++co) {
                const int o = co * 64 + c * 4;
                #pragma unroll
                for (int it = 0; it < 4; ++it) {
                    const int m = mb + g * 16 + it * 4 + r;
                    float4 k4 = *reinterpret_cast<const float4*>(kf + (size_t)m * CC + o);
                    float kd = k4.x * q4[co].x + k4.y * q4[co].y +
                               k4.z * q4[co].z + k4.w * q4[co].w;
                    acc[it][2 * co    ] += (c & 8) ? 0.f : kd;
                    acc[it][2 * co + 1] += (c & 8) ? kd : 0.f;
                }
            }
            #pragma unroll
            for (int it = 0; it < 4; ++it) {
                float u0 = reduce8(acc[it], c);
                if (!(c & 8)) {
                    int h = (c & 1) * 4 + (c & 2) + ((c >> 2) & 1);
                    s_lds[h][mb + g * 16 + it * 4 + r] = u0;  // seed (banks 4h+r)
                }
            }
        }
    }

    // ---- E-pass: stream E[n] (nontemporal, rotated phase order), 2-deep pipeline ----
    const float* Ebase = E + (size_t)n * NN * CC;
    {
        vf4 ebuf[2][4];
        // phase 0 (rotated): gg=Rg, cc=Rc
        #pragma unroll
        for (int it = 0; it < 4; ++it)
            ebuf[0][it] = __builtin_nontemporal_load(reinterpret_cast<const vf4*>(
                Ebase + (size_t)(mb + Rg * 16 + it * 4 + r) * CC + Rc * 64 + c * 4));

        for (int g = 0; g < 4; ++g) {
            const int gg = (g + Rg) & 3;
            float acc[4][HH];
            #pragma unroll
            for (int it = 0; it < 4; ++it)
                #pragma unroll
                for (int h = 0; h < HH; ++h) acc[it][h] = 0.f;

            #pragma unroll
            for (int co = 0; co < 4; ++co) {
                const int cur = co & 1;          // parity of gc=g*4+co (g*4 even)
                const int cc_ = (co + Rc) & 3;
                // prefetch next rotated phase into the other buffer
                if (g < 3 || co < 3) {
                    const int cn = (co + 1) & 3;
                    const int gn = (co == 3) ? g + 1 : g;
                    const int ggn = (gn + Rg) & 3;
                    const int ccn = (cn + Rc) & 3;
                    #pragma unroll
                    for (int it = 0; it < 4; ++it)
                        ebuf[cur ^ 1][it] = __builtin_nontemporal_load(
                            reinterpret_cast<const vf4*>(
                                Ebase + (size_t)(mb + ggn * 16 + it * 4 + r) * CC +
                                ccn * 64 + c * 4));
                }
                const int o = cc_ * 64 + c * 4;
                #pragma unroll
                for (int h = 0; h < HH; ++h) {
                    float4 wv = *reinterpret_cast<const float4*>(&qw_lds[h][o]);
                    #pragma unroll
                    for (int it = 0; it < 4; ++it)
                        acc[it][h] += ebuf[cur][it][0] * wv.x + ebuf[cur][it][1] * wv.y +
                                      ebuf[cur][it][2] * wv.z + ebuf[cur][it][3] * wv.w;
                }
            }
            #pragma unroll
            for (int it = 0; it < 4; ++it) {
                float u0 = reduce8(acc[it], c);
                if (!(c & 8)) {
                    int h = (c & 1) * 4 + (c & 2) + ((c >> 2) & 1);
                    s_lds[h][mb + gg * 16 + it * 4 + r] += u0;
                }
            }
        }
    }
    __syncthreads();

    // softmax: wave w handles head w over all 512 m (bias + scale folded)
    {
        const int h = w;
        const float qb = qbp[(size_t)n * HH + h];
        const float scale = 0.17677669529663687f;  // 1/sqrt(32)
        float vals[8];
        float mx = -1e30f;
        #pragma unroll
        for (int i = 0; i < 8; ++i) {
            vals[i] = (s_lds[h][l + i * 64] + qb) * scale;
            mx = fmaxf(mx, vals[i]);
        }
        #pragma unroll
        for (int off = 32; off > 0; off >>= 1) mx = fmaxf(mx, __shfl_xor(mx, off));
        float sum = 0.f;
        #pragma unroll
        for (int i = 0; i < 8; ++i) { vals[i] = __expf(vals[i] - mx); sum += vals[i]; }
        #pragma unroll
        for (int off = 32; off > 0; off >>= 1) sum += __shfl_xor(sum, off);
        float inv = 1.0f / sum;
        #pragma unroll
        for (int i = 0; i < 8; ++i) {
            float p = vals[i] * inv;
            int m = l + i * 64;
            s_lds[h][m] = p;
            __builtin_nontemporal_store(p, attn_out + ((size_t)h * NN + n) * NN + m);
        }
    }
    __syncthreads();

    // hidden[n][j] = sum_m attn[h][m] * v[m][j], h = j>>5 (v is L2-resident)
    {
        float* part = &qw_lds[0][0];       // reuse qw_lds (8 KB) as partial buffer
        const int quad = t & 63;           // output cols quad*4..quad*4+3
        const int slice = w;               // m slice of 64
        const int h = quad >> 3;
        float4 a4 = {0.f, 0.f, 0.f, 0.f};
        const float* vb = vf + quad * 4;
        for (int mm = 0; mm < 64; ++mm) {
            int m = slice * 64 + mm;
            float a = s_lds[h][m];
            float4 vv = *reinterpret_cast<const float4*>(vb + (size_t)m * CC);
            a4.x += a * vv.x; a4.y += a * vv.y; a4.z += a * vv.z; a4.w += a * vv.w;
        }
        __syncthreads();                    // qw_lds reads are long done; re-purpose
        *reinterpret_cast<float4*>(&part[slice * 256 + quad * 4]) = a4;
    }
    __syncthreads();
    if (t < 256) {
        const float* part = &qw_lds[0][0];
        float s = 0.f;
        #pragma unroll
        for (int sl = 0; sl < 8; ++sl) s += part[sl * 256 + t];
        out_hidden[(size_t)n * CC + t] = s;
    }
}

// ---------------- launch ----------------
extern "C" void kernel_launch(void* const* d_in, const int* in_sizes, int n_in,
                              void* d_out, int out_size, void* d_ws, size_t ws_size,
                              hipStream_t stream) {
    const float* xq = (const float*)d_in[0];
    const float* xk = (const float*)d_in[1];
    const float* xv = (const float*)d_in[2];
    const float* E  = (const float*)d_in[3];
    const float* Wq = (const float*)d_in[4];
    const float* bq = (const float*)d_in[5];
    const float* Wk = (const float*)d_in[6];
    const float* bk = (const float*)d_in[7];
    const float* Wv = (const float*)d_in[8];
    const float* bv = (const float*)d_in[9];
    const float* Wp = (const float*)d_in[10];
    const float* bp = (const float*)d_in[11];

    float* ws = (float*)d_ws;
    float* qf  = ws;                        // 512*256
    float* kf  = qf + NN * CC;              // 512*256
    float* vf  = kf + NN * CC;              // 512*256
    float* qw  = vf + NN * CC;              // 512*8*256
    float* qbp = qw + (size_t)NN * HH * CC; // 512*8

    float* out_hidden = (float*)d_out;            // 512*256
    float* out_attn   = out_hidden + NN * CC;     // 8*512*512

    proj_kernel<<<NN / 2, 512, 0, stream>>>(xq, xk, xv, Wq, bq, Wk, bk, Wv, bv, Wp, bp,
                                            qf, kf, vf, qw, qbp);
    attn_kernel<<<NN, 512, 0, stream>>>(E, qf, kf, vf, qw, qbp, out_attn, out_hidden);
}